// Round 4
// baseline (583.560 us; speedup 1.0000x reference)
//
#include <hip/hip_runtime.h>

// HierarchicalRouter: 32768 tokens x D=2048 fp32.
// Outputs (concat in d_out): final_weights [32768,2], dispatch_mask [32768,64], router_loss [1].
//
// Round-4 synthesis of three measured lessons:
//  * r2: weight loads from global serialize on L2 latency inside the FMA stream
//    (vmcnt in-order completion) -> weights must come from LDS via ds_read.
//  * r3: __launch_bounds__(256,4) capped VGPR at 128 < ~140 needed -> acc[4][20]
//    spilled to scratch (VGPR_Count=64, WRITE_SIZE 10->80 MB). Use (256,3): 168 budget.
//  * r0: synchronous stage->barrier->compute serializes staging with compute. Here the
//    weight chunk for c+1 streams via async global_load_lds into a double buffer WHILE
//    chunk c computes; the end-of-half-iter __syncthreads drains vmcnt (m97 pattern).
//  x stays in registers (ping-pong prefetch, nontemporal): its latency hides under the
//  compute phase; LDS = 2x20KB weights -> 3 blocks/CU, 12 waves/CU.
//
// Bit-exactness contract (round-1 lesson: group logits are near-ties; accumulation
// order is part of the contract): per-lane slice layout (lane*4 within each 256-float
// chunk), chunk order 0..7, the dot4 expression, the 64-lane XOR butterfly and the
// epilogue are verbatim from the passing round-0/2/3 kernels. Weight values through
// LDS are byte-identical to global.

#define NTOK    32768
#define DIM     2048
#define NG      16      // router groups (rows of Wg)
#define GS      4       // experts per group (rows of We)
#define NE      64      // total experts
#define NR      20      // NG + GS stacked weight rows
#define DC      256     // D-chunk: 64 lanes x float4
#define NCHUNK  (DIM / DC)
#define TPB     256
#define TPW     4       // tokens per wave
#define TPBK    16      // tokens per block (4 waves * 4)
#define WCH     (NR * DC)   // floats per staged weight chunk (5120 = 20 KB)
#define NSHADOW 32      // shadow copies of expert_load to spread atomic contention

typedef float f4 __attribute__((ext_vector_type(4)));

__device__ __forceinline__ f4 ldnt(const float* p) {
    return __builtin_nontemporal_load((const f4*)p);
}

__device__ __forceinline__ void gl_lds16(const float* g, float* l) {
    // async 16B/lane global->LDS; LDS dst = wave-uniform base + lane*16.
    __builtin_amdgcn_global_load_lds(
        (const __attribute__((address_space(1))) void*)g,
        (__attribute__((address_space(3))) void*)l,
        16, 0, 0);
}

__global__ __launch_bounds__(TPB, 3) void router_main(
    const float* __restrict__ x,
    const float* __restrict__ Wg,
    const float* __restrict__ We,
    float* __restrict__ fw_out,
    float* __restrict__ dm_out,
    float* __restrict__ ws)
{
    __shared__ float wbuf[2][WCH];    // 2 x 20 KB weight-chunk double buffer
    __shared__ float lds_load[NE];    // per-block expert load
    __shared__ float lds_z;           // per-block z-loss partial

    const int tid  = threadIdx.x;
    const int lane = tid & 63;
    const int wave = tid >> 6;
    const long t_base = (long)blockIdx.x * TPBK + wave * TPW;

    if (tid < NE) lds_load[tid] = 0.0f;
    if (tid == 0) lds_z = 0.0f;

    // ---- weight-chunk staging: wave stages rows {wave, wave+4, wave+8, wave+12}
    //      from Wg and row wave from We; 5 async issues per thread, 20 KB total ----
    const float* wg_l = Wg + lane * 4;   // per-lane global column base
    const float* we_l = We + lane * 4;
    auto stage_w = [&](int c, float* dst) {
        #pragma unroll
        for (int k = 0; k < 4; ++k) {
            const int r = k * 4 + wave;
            gl_lds16(wg_l + (size_t)r * DIM + c * DC, dst + r * DC);
        }
        gl_lds16(we_l + (size_t)wave * DIM + c * DC, dst + (NG + wave) * DC);
    };

    float acc[TPW][NR];
    #pragma unroll
    for (int t = 0; t < TPW; ++t)
        #pragma unroll
        for (int r = 0; r < NR; ++r) acc[t][r] = 0.0f;

    const float* xp = x + (size_t)t_base * DIM + lane * 4;   // + t*DIM + c*DC

    // ---- prologue: stage weight chunk 0; load x chunk 0 into regs ----
    stage_w(0, &wbuf[0][0]);
    f4 xa[TPW], xb[TPW];
    #pragma unroll
    for (int t = 0; t < TPW; ++t) xa[t] = ldnt(xp + (size_t)t * DIM);
    __syncthreads();   // drains vmcnt: wbuf[0] + xa ready (also covers lds_load init)

    // ---- main loop: 2 chunks/iter; stage c+1 & prefetch x while computing c ----
    #pragma unroll 1
    for (int c = 0; c < NCHUNK; c += 2) {
        stage_w(c + 1, &wbuf[1][0]);
        #pragma unroll
        for (int t = 0; t < TPW; ++t)
            xb[t] = ldnt(xp + (size_t)t * DIM + (c + 1) * DC);

        #pragma unroll
        for (int r = 0; r < NR; ++r) {
            f4 w = *(const f4*)(&wbuf[0][r * DC + lane * 4]);   // ds_read_b128
            #pragma unroll
            for (int t = 0; t < TPW; ++t) {
                acc[t][r] += xa[t].x * w.x + xa[t].y * w.y
                           + xa[t].z * w.z + xa[t].w * w.w;
            }
        }
        __syncthreads();   // wbuf[1]+xb complete; all waves done reading wbuf[0]

        if (c + 2 < NCHUNK) {
            stage_w(c + 2, &wbuf[0][0]);
            #pragma unroll
            for (int t = 0; t < TPW; ++t)
                xa[t] = ldnt(xp + (size_t)t * DIM + (c + 2) * DC);
        }

        #pragma unroll
        for (int r = 0; r < NR; ++r) {
            f4 w = *(const f4*)(&wbuf[1][r * DC + lane * 4]);
            #pragma unroll
            for (int t = 0; t < TPW; ++t) {
                acc[t][r] += xb[t].x * w.x + xb[t].y * w.y
                           + xb[t].z * w.z + xb[t].w * w.w;
            }
        }
        __syncthreads();   // wbuf[0]+xa complete; all waves done reading wbuf[1]
    }

    // ---- full-wave butterfly reduce (identical to round-0) ----
    #pragma unroll
    for (int t = 0; t < TPW; ++t)
        #pragma unroll
        for (int r = 0; r < NR; ++r) {
            float v = acc[t][r];
            #pragma unroll
            for (int s = 32; s > 0; s >>= 1) v += __shfl_xor(v, s, 64);
            acc[t][r] = v;
        }

    // ---- epilogue: tokens sequentially; scalar-only state (identical to round-0) ----
    #pragma unroll
    for (int t = 0; t < TPW; ++t) {
        // group softmax + top-1 (strict > = first-index-wins, matches np)
        float m16 = acc[t][0];
        #pragma unroll
        for (int r = 1; r < NG; ++r) m16 = fmaxf(m16, acc[t][r]);
        float den = 0.0f, bm = -1.0f; int gi = 0;
        #pragma unroll
        for (int r = 0; r < NG; ++r) {
            float e = expf(acc[t][r] - m16);
            den += e;
            if (e > bm) { bm = e; gi = r; }
        }
        float gw = bm / den;   // chosen_group_w (max softmax prob)

        // local softmax (4) + top-2
        float m4 = fmaxf(fmaxf(acc[t][NG + 0], acc[t][NG + 1]),
                         fmaxf(acc[t][NG + 2], acc[t][NG + 3]));
        float pr[GS]; float s4 = 0.0f;
        #pragma unroll
        for (int r = 0; r < GS; ++r) { pr[r] = expf(acc[t][NG + r] - m4); s4 += pr[r]; }
        float inv4 = 1.0f / s4;
        #pragma unroll
        for (int r = 0; r < GS; ++r) pr[r] *= inv4;

        int i0 = 0; float v0 = pr[0];
        #pragma unroll
        for (int r = 1; r < GS; ++r) if (pr[r] > v0) { v0 = pr[r]; i0 = r; }
        int i1 = -1; float v1 = -1.0f;
        #pragma unroll
        for (int r = 0; r < GS; ++r) if (r != i0 && pr[r] > v1) { v1 = pr[r]; i1 = r; }

        float nrm = v0 + v1 + 1e-7f;
        float sf0 = gw * (v0 / nrm);
        float sf1 = gw * (v1 / nrm);
        int   se0 = (gi << 2) + i0;
        int   se1 = (gi << 2) + i1;

        float sg = 0.0f;
        #pragma unroll
        for (int r = 0; r < NG; ++r) sg += acc[t][r] * acc[t][r];
        float sl = 0.0f;
        #pragma unroll
        for (int r = 0; r < GS; ++r) sl += acc[t][NG + r] * acc[t][NG + r];
        float sz = sg * (1.0f / 16.0f) + sl * 0.25f;   // per-token z contribution

        const long tok = t_base + t;
        if (lane < 16) {
            int col4 = lane * 4;
            float4 v;
            v.x = (col4 + 0 == se0) ? sf0 : (col4 + 0 == se1) ? sf1 : 0.0f;
            v.y = (col4 + 1 == se0) ? sf0 : (col4 + 1 == se1) ? sf1 : 0.0f;
            v.z = (col4 + 2 == se0) ? sf0 : (col4 + 2 == se1) ? sf1 : 0.0f;
            v.w = (col4 + 3 == se0) ? sf0 : (col4 + 3 == se1) ? sf1 : 0.0f;
            *(float4*)(dm_out + (size_t)tok * NE + col4) = v;  // 16 lanes x 16B = 256B row
        } else if (lane == 16) {
            *(float2*)(fw_out + tok * 2) = make_float2(sf0, sf1);
        } else if (lane == 17) {
            atomicAdd(&lds_load[se0], sf0);
        } else if (lane == 18) {
            atomicAdd(&lds_load[se1], sf1);
        } else if (lane == 19) {
            atomicAdd(&lds_z, sz);
        }
    }

    __syncthreads();
    if (tid < NE) atomicAdd(&ws[(blockIdx.x & (NSHADOW - 1)) * NE + tid], lds_load[tid]);
    if (tid == 0) atomicAdd(&ws[NSHADOW * NE], lds_z);
}

__global__ void router_finalize(const float* __restrict__ ws, float* __restrict__ out_loss)
{
    int e = threadIdx.x;  // 64 threads = 1 wave
    float load = 0.0f;
    #pragma unroll
    for (int s = 0; s < NSHADOW; ++s) load += ws[s * NE + e];
    float tot = load;
    #pragma unroll
    for (int s = 32; s > 0; s >>= 1) tot += __shfl_xor(tot, s, 64);
    float target = tot * (1.0f / NE);
    float dev = load - target;
    float sq = dev * dev;
    #pragma unroll
    for (int s = 32; s > 0; s >>= 1) sq += __shfl_xor(sq, s, 64);
    if (e == 0) {
        float lb = sq * (1.0f / NE);
        float z  = ws[NSHADOW * NE] * (1.0f / NTOK);
        out_loss[0] = 0.001f * (lb + z);
    }
}

extern "C" void kernel_launch(void* const* d_in, const int* in_sizes, int n_in,
                              void* d_out, int out_size, void* d_ws, size_t ws_size,
                              hipStream_t stream)
{
    const float* x  = (const float*)d_in[0];
    const float* Wg = (const float*)d_in[1];
    const float* We = (const float*)d_in[2];
    float* out = (float*)d_out;
    float* fw  = out;                                         // [32768, 2]
    float* dm  = out + (size_t)NTOK * 2;                      // [32768, 64]
    float* ls  = out + (size_t)NTOK * 2 + (size_t)NTOK * NE;  // [1]
    float* ws  = (float*)d_ws;

    hipMemsetAsync(ws, 0, (NSHADOW * NE + 1) * sizeof(float), stream);
    router_main<<<NTOK / TPBK, TPB, 0, stream>>>(x, Wg, We, fw, dm, ws);
    router_finalize<<<1, 64, 0, stream>>>(ws, ls);
}

// Round 5
// 417.795 us; speedup vs baseline: 1.3968x; 1.3968x over previous
//
#include <hip/hip_runtime.h>

// HierarchicalRouter: 32768 tokens x D=2048 fp32.
// Outputs (concat in d_out): final_weights [32768,2], dispatch_mask [32768,64], router_loss [1].
//
// Round-5: round-4's structure was right; its launch_bounds was wrong. rocprof's
// VGPR_Count is in granules of 2: r3 "64"=128 phys (=(256,4) cap), r4 "84"=168 phys
// (=(256,3) cap) -> the allocator was capped under the ~200-reg need and spilled acc
// to scratch (20 regs x 8B x 8 chunks x 524288 threads ~ 670 MB == the observed
// WRITE_SIZE blow-up 10->555 MB). Fix: __launch_bounds__(256,2) (256-reg budget).
// Structure (unchanged from r4, which passed correctness):
//  * weights: async global_load_lds into a 2x20KB double buffer; compute reads them
//    via ds_read_b128 (no vmcnt dependency in the FMA stream — r2 lesson).
//  * x: register ping-pong prefetch, nontemporal (doesn't evict L2-resident weights).
//  * MLP at 2 blocks/CU: 32 KB/CU x-loads + 40 KB/CU weight staging in flight -> HBM-rate.
//
// Bit-exactness contract (round-1 lesson: group logits are near-ties; accumulation
// order is part of the contract): per-lane slice layout (lane*4 within each 256-float
// chunk), chunk order 0..7, the dot4 expression, the 64-lane XOR butterfly and the
// epilogue are verbatim from the passing round-0/2/3/4 kernels.

#define NTOK    32768
#define DIM     2048
#define NG      16      // router groups (rows of Wg)
#define GS      4       // experts per group (rows of We)
#define NE      64      // total experts
#define NR      20      // NG + GS stacked weight rows
#define DC      256     // D-chunk: 64 lanes x float4
#define NCHUNK  (DIM / DC)
#define TPB     256
#define TPW     4       // tokens per wave
#define TPBK    16      // tokens per block (4 waves * 4)
#define WCH     (NR * DC)   // floats per staged weight chunk (5120 = 20 KB)
#define NSHADOW 32      // shadow copies of expert_load to spread atomic contention

typedef float f4 __attribute__((ext_vector_type(4)));

__device__ __forceinline__ f4 ldnt(const float* p) {
    return __builtin_nontemporal_load((const f4*)p);
}

__device__ __forceinline__ void gl_lds16(const float* g, float* l) {
    // async 16B/lane global->LDS; LDS dst = wave-uniform base + lane*16.
    __builtin_amdgcn_global_load_lds(
        (const __attribute__((address_space(1))) void*)g,
        (__attribute__((address_space(3))) void*)l,
        16, 0, 0);
}

__global__ __launch_bounds__(TPB, 2) void router_main(
    const float* __restrict__ x,
    const float* __restrict__ Wg,
    const float* __restrict__ We,
    float* __restrict__ fw_out,
    float* __restrict__ dm_out,
    float* __restrict__ ws)
{
    __shared__ float wbuf[2][WCH];    // 2 x 20 KB weight-chunk double buffer
    __shared__ float lds_load[NE];    // per-block expert load
    __shared__ float lds_z;           // per-block z-loss partial

    const int tid  = threadIdx.x;
    const int lane = tid & 63;
    const int wave = tid >> 6;
    const long t_base = (long)blockIdx.x * TPBK + wave * TPW;

    if (tid < NE) lds_load[tid] = 0.0f;
    if (tid == 0) lds_z = 0.0f;

    // ---- weight-chunk staging: wave stages rows {wave, wave+4, wave+8, wave+12}
    //      from Wg and row wave from We; 5 async issues per thread, 20 KB total ----
    const float* wg_l = Wg + lane * 4;   // per-lane global column base
    const float* we_l = We + lane * 4;
    auto stage_w = [&](int c, float* dst) {
        #pragma unroll
        for (int k = 0; k < 4; ++k) {
            const int r = k * 4 + wave;
            gl_lds16(wg_l + (size_t)r * DIM + c * DC, dst + r * DC);
        }
        gl_lds16(we_l + (size_t)wave * DIM + c * DC, dst + (NG + wave) * DC);
    };

    float acc[TPW][NR];
    #pragma unroll
    for (int t = 0; t < TPW; ++t)
        #pragma unroll
        for (int r = 0; r < NR; ++r) acc[t][r] = 0.0f;

    const float* xp = x + (size_t)t_base * DIM + lane * 4;   // + t*DIM + c*DC

    // ---- prologue: stage weight chunk 0; load x chunk 0 into regs ----
    stage_w(0, &wbuf[0][0]);
    f4 xa[TPW], xb[TPW];
    #pragma unroll
    for (int t = 0; t < TPW; ++t) xa[t] = ldnt(xp + (size_t)t * DIM);
    __syncthreads();   // drains vmcnt: wbuf[0] + xa ready (also covers lds_load init)

    // ---- main loop: 2 chunks/iter; stage c+1 & prefetch x while computing c ----
    #pragma unroll 1
    for (int c = 0; c < NCHUNK; c += 2) {
        stage_w(c + 1, &wbuf[1][0]);
        #pragma unroll
        for (int t = 0; t < TPW; ++t)
            xb[t] = ldnt(xp + (size_t)t * DIM + (c + 1) * DC);

        #pragma unroll
        for (int r = 0; r < NR; ++r) {
            f4 w = *(const f4*)(&wbuf[0][r * DC + lane * 4]);   // ds_read_b128
            #pragma unroll
            for (int t = 0; t < TPW; ++t) {
                acc[t][r] += xa[t].x * w.x + xa[t].y * w.y
                           + xa[t].z * w.z + xa[t].w * w.w;
            }
        }
        __syncthreads();   // wbuf[1]+xb complete; all waves done reading wbuf[0]

        if (c + 2 < NCHUNK) {
            stage_w(c + 2, &wbuf[0][0]);
            #pragma unroll
            for (int t = 0; t < TPW; ++t)
                xa[t] = ldnt(xp + (size_t)t * DIM + (c + 2) * DC);
        }

        #pragma unroll
        for (int r = 0; r < NR; ++r) {
            f4 w = *(const f4*)(&wbuf[1][r * DC + lane * 4]);
            #pragma unroll
            for (int t = 0; t < TPW; ++t) {
                acc[t][r] += xb[t].x * w.x + xb[t].y * w.y
                           + xb[t].z * w.z + xb[t].w * w.w;
            }
        }
        __syncthreads();   // wbuf[0]+xa complete; all waves done reading wbuf[1]
    }

    // ---- full-wave butterfly reduce (identical to round-0) ----
    #pragma unroll
    for (int t = 0; t < TPW; ++t)
        #pragma unroll
        for (int r = 0; r < NR; ++r) {
            float v = acc[t][r];
            #pragma unroll
            for (int s = 32; s > 0; s >>= 1) v += __shfl_xor(v, s, 64);
            acc[t][r] = v;
        }

    // ---- epilogue: tokens sequentially; scalar-only state (identical to round-0) ----
    #pragma unroll
    for (int t = 0; t < TPW; ++t) {
        // group softmax + top-1 (strict > = first-index-wins, matches np)
        float m16 = acc[t][0];
        #pragma unroll
        for (int r = 1; r < NG; ++r) m16 = fmaxf(m16, acc[t][r]);
        float den = 0.0f, bm = -1.0f; int gi = 0;
        #pragma unroll
        for (int r = 0; r < NG; ++r) {
            float e = expf(acc[t][r] - m16);
            den += e;
            if (e > bm) { bm = e; gi = r; }
        }
        float gw = bm / den;   // chosen_group_w (max softmax prob)

        // local softmax (4) + top-2
        float m4 = fmaxf(fmaxf(acc[t][NG + 0], acc[t][NG + 1]),
                         fmaxf(acc[t][NG + 2], acc[t][NG + 3]));
        float pr[GS]; float s4 = 0.0f;
        #pragma unroll
        for (int r = 0; r < GS; ++r) { pr[r] = expf(acc[t][NG + r] - m4); s4 += pr[r]; }
        float inv4 = 1.0f / s4;
        #pragma unroll
        for (int r = 0; r < GS; ++r) pr[r] *= inv4;

        int i0 = 0; float v0 = pr[0];
        #pragma unroll
        for (int r = 1; r < GS; ++r) if (pr[r] > v0) { v0 = pr[r]; i0 = r; }
        int i1 = -1; float v1 = -1.0f;
        #pragma unroll
        for (int r = 0; r < GS; ++r) if (r != i0 && pr[r] > v1) { v1 = pr[r]; i1 = r; }

        float nrm = v0 + v1 + 1e-7f;
        float sf0 = gw * (v0 / nrm);
        float sf1 = gw * (v1 / nrm);
        int   se0 = (gi << 2) + i0;
        int   se1 = (gi << 2) + i1;

        float sg = 0.0f;
        #pragma unroll
        for (int r = 0; r < NG; ++r) sg += acc[t][r] * acc[t][r];
        float sl = 0.0f;
        #pragma unroll
        for (int r = 0; r < GS; ++r) sl += acc[t][NG + r] * acc[t][NG + r];
        float sz = sg * (1.0f / 16.0f) + sl * 0.25f;   // per-token z contribution

        const long tok = t_base + t;
        if (lane < 16) {
            int col4 = lane * 4;
            float4 v;
            v.x = (col4 + 0 == se0) ? sf0 : (col4 + 0 == se1) ? sf1 : 0.0f;
            v.y = (col4 + 1 == se0) ? sf0 : (col4 + 1 == se1) ? sf1 : 0.0f;
            v.z = (col4 + 2 == se0) ? sf0 : (col4 + 2 == se1) ? sf1 : 0.0f;
            v.w = (col4 + 3 == se0) ? sf0 : (col4 + 3 == se1) ? sf1 : 0.0f;
            *(float4*)(dm_out + (size_t)tok * NE + col4) = v;  // 16 lanes x 16B = 256B row
        } else if (lane == 16) {
            *(float2*)(fw_out + tok * 2) = make_float2(sf0, sf1);
        } else if (lane == 17) {
            atomicAdd(&lds_load[se0], sf0);
        } else if (lane == 18) {
            atomicAdd(&lds_load[se1], sf1);
        } else if (lane == 19) {
            atomicAdd(&lds_z, sz);
        }
    }

    __syncthreads();
    if (tid < NE) atomicAdd(&ws[(blockIdx.x & (NSHADOW - 1)) * NE + tid], lds_load[tid]);
    if (tid == 0) atomicAdd(&ws[NSHADOW * NE], lds_z);
}

__global__ void router_finalize(const float* __restrict__ ws, float* __restrict__ out_loss)
{
    int e = threadIdx.x;  // 64 threads = 1 wave
    float load = 0.0f;
    #pragma unroll
    for (int s = 0; s < NSHADOW; ++s) load += ws[s * NE + e];
    float tot = load;
    #pragma unroll
    for (int s = 32; s > 0; s >>= 1) tot += __shfl_xor(tot, s, 64);
    float target = tot * (1.0f / NE);
    float dev = load - target;
    float sq = dev * dev;
    #pragma unroll
    for (int s = 32; s > 0; s >>= 1) sq += __shfl_xor(sq, s, 64);
    if (e == 0) {
        float lb = sq * (1.0f / NE);
        float z  = ws[NSHADOW * NE] * (1.0f / NTOK);
        out_loss[0] = 0.001f * (lb + z);
    }
}

extern "C" void kernel_launch(void* const* d_in, const int* in_sizes, int n_in,
                              void* d_out, int out_size, void* d_ws, size_t ws_size,
                              hipStream_t stream)
{
    const float* x  = (const float*)d_in[0];
    const float* Wg = (const float*)d_in[1];
    const float* We = (const float*)d_in[2];
    float* out = (float*)d_out;
    float* fw  = out;                                         // [32768, 2]
    float* dm  = out + (size_t)NTOK * 2;                      // [32768, 64]
    float* ls  = out + (size_t)NTOK * 2 + (size_t)NTOK * NE;  // [1]
    float* ws  = (float*)d_ws;

    hipMemsetAsync(ws, 0, (NSHADOW * NE + 1) * sizeof(float), stream);
    router_main<<<NTOK / TPBK, TPB, 0, stream>>>(x, Wg, We, fw, dm, ws);
    router_finalize<<<1, 64, 0, stream>>>(ws, ls);
}